// Round 5
// baseline (195.286 us; speedup 1.0000x reference)
//
#include <hip/hip_runtime.h>
#include <math.h>

#define CHI 64
#define CHO 64
#define BB 4
#define HH 128
#define WW 256
#define HWSZ (HH * WW)     // 32768 px per channel plane
#define KTOT 576           // K = khat*64 + c
#define NSTEP 18           // 576 / 32

typedef float f32x4 __attribute__((ext_vector_type(4)));
typedef short bf16x8 __attribute__((ext_vector_type(8)));

// Device-global staging (no ws_size dependence).
__device__ __attribute__((aligned(16))) ushort g_xT[BB * HWSZ * CHI];  // NHWC bf16: [b*HWSZ+px][c]
__device__ __attribute__((aligned(16))) ushort g_wB[CHO * KTOT];       // [o][khat*64+c]
__device__ __attribute__((aligned(16))) ushort g_wOffB[32 * KTOT];     // [co][khat*64+c], co 27..31 = 0

__device__ __forceinline__ ushort f2bf(float f) {
    uint32_t u = __builtin_bit_cast(uint32_t, f);
    u = (u + 0x7fffu + ((u >> 16) & 1u)) >> 16;   // RNE
    return (ushort)u;
}
__device__ __forceinline__ uint32_t pk2(float a, float b) {
    return (uint32_t)f2bf(a) | ((uint32_t)f2bf(b) << 16);
}
__device__ __forceinline__ float bflo(uint32_t u) { return __builtin_bit_cast(float, u << 16); }
__device__ __forceinline__ float bfhi(uint32_t u) { return __builtin_bit_cast(float, u & 0xffff0000u); }
__device__ __forceinline__ uint32_t cvtpk(float lo, float hi) {
    uint32_t r;
    asm("v_cvt_pk_bf16_f32 %0, %1, %2" : "=v"(r) : "v"(lo), "v"(hi));
    return r;
}

__global__ void prep(const float* __restrict__ weight, const float* __restrict__ w_off) {
    int idx = blockIdx.x * 256 + threadIdx.x;
    if (idx < CHO * KTOT) {
        int o = idx / KTOT, K = idx % KTOT, kh = K >> 6, c = K & 63;
        g_wB[idx] = f2bf(weight[(o * CHI + c) * 9 + kh]);
    }
    if (idx < 32 * KTOT) {
        int o = idx / KTOT, K = idx % KTOT, kh = K >> 6, c = K & 63;
        g_wOffB[idx] = (o < 27) ? f2bf(w_off[(o * CHI + c) * 9 + kh]) : (ushort)0;
    }
}

// NCHW f32 -> NHWC bf16 transpose. Block = 64 px x 64 ch tile.
__global__ __launch_bounds__(256) void transform(const float* __restrict__ x) {
    __shared__ ushort t[64][68];
    const int tid = threadIdx.x;
    const int wv = tid >> 6, lane = tid & 63;
    const int pb = blockIdx.x * 64;
    const int b = pb >> 15;
    const int pin = pb & (HWSZ - 1);
    const float* __restrict__ xb = x + (size_t)b * CHI * HWSZ + pin;
#pragma unroll
    for (int i = 0; i < 16; ++i) {
        const int c = wv * 16 + i;
        t[lane][c] = f2bf(xb[(size_t)c * HWSZ + lane]);
    }
    __syncthreads();
    const int px = tid >> 2, cb = (tid & 3) * 16;
    const uint32_t* __restrict__ row = (const uint32_t*)&t[px][cb];
    uint4 v0, v1;
    v0.x = row[0]; v0.y = row[1]; v0.z = row[2]; v0.w = row[3];
    v1.x = row[4]; v1.y = row[5]; v1.z = row[6]; v1.w = row[7];
    uint4* __restrict__ dst = (uint4*)&g_xT[(size_t)(pb + px) * CHI + cb];
    dst[0] = v0; dst[1] = v1;
}

union U8 { uint32_t u[4]; bf16x8 v; };

__device__ __forceinline__ bf16x8 bilerp8(bf16x8 v00, bf16x8 v01, bf16x8 v10, bf16x8 v11,
                                          float w00, float w01, float w10, float w11) {
    U8 C00, C01, C10, C11, A;
    C00.v = v00; C01.v = v01; C10.v = v10; C11.v = v11;
#pragma unroll
    for (int j = 0; j < 4; ++j) {
        float se = w00 * bflo(C00.u[j]);
        se = fmaf(w01, bflo(C01.u[j]), se);
        se = fmaf(w10, bflo(C10.u[j]), se);
        se = fmaf(w11, bflo(C11.u[j]), se);
        float so = w00 * bfhi(C00.u[j]);
        so = fmaf(w01, bfhi(C01.u[j]), so);
        so = fmaf(w10, bfhi(C10.u[j]), so);
        so = fmaf(w11, bfhi(C11.u[j]), so);
        A.u[j] = cvtpk(se, so);
    }
    return A.v;
}

// 256 threads = 4 waves; wave = 16 consecutive px; block = 64 px.
__global__ __launch_bounds__(256) void dcn_mfma(
    const float* __restrict__ b_off, const float* __restrict__ bias,
    float* __restrict__ out)
{
    __shared__ float om_lds[4][16][33];
    __shared__ uint4 po_lds[4][16][9];     // corner byte offsets {o00,o01,o10,o11}
    __shared__ uint2 pw_lds[4][16][9];     // packed bf16 corner weights {w00|w01, w10|w11}

    const int tid = threadIdx.x;
    const int wv = tid >> 6, l = tid & 63;
    const int lr = l & 15, lg = l >> 4;
    const int blk = blockIdx.x;
    const int b = blk >> 9;
    const int pbase = (blk & 511) * 64 + wv * 16;
    const char* __restrict__ xtb = (const char*)g_xT + (size_t)b * HWSZ * (CHI * 2);

    // ---------------- Phase 1: offset conv (16px x 27ch) via MFMA, depth-1 prefetch ----------------
    {
        const int p = pbase + lr;
        const int h = p >> 8, w = p & 255;
        f32x4 acc0 = {0.f, 0.f, 0.f, 0.f}, acc1 = {0.f, 0.f, 0.f, 0.f};

        U8 Acur; bool vcur;
        {
            const int iy = h - 1, ix = w - 1;   // s=0 -> kh=0
            vcur = ((unsigned)iy < HH) & ((unsigned)ix < WW);
            const int pidx = vcur ? (iy * WW + ix) : 0;
            Acur.v = *(const bf16x8*)(xtb + (size_t)pidx * (CHI * 2) + (lg * 8) * 2);
        }
#pragma unroll 1
        for (int s = 0; s < NSTEP; ++s) {
            U8 Anext; bool vnext = true;
            if (s < NSTEP - 1) {
                const int sn = s + 1, khn = sn >> 1;
                const int iy = h + (khn / 3) - 1, ix = w + (khn % 3) - 1;
                vnext = ((unsigned)iy < HH) & ((unsigned)ix < WW);
                const int pidx = vnext ? (iy * WW + ix) : 0;
                Anext.v = *(const bf16x8*)(xtb + (size_t)pidx * (CHI * 2) + ((sn & 1) * 32 + lg * 8) * 2);
            }
            if (!vcur) { Acur.u[0] = 0; Acur.u[1] = 0; Acur.u[2] = 0; Acur.u[3] = 0; }
            const int koff = s * 32 + lg * 8;
            bf16x8 b0 = *(const bf16x8*)&g_wOffB[(size_t)lr * KTOT + koff];
            bf16x8 b1 = *(const bf16x8*)&g_wOffB[(size_t)(16 + lr) * KTOT + koff];
            acc0 = __builtin_amdgcn_mfma_f32_16x16x32_bf16(Acur.v, b0, acc0, 0, 0, 0);
            acc1 = __builtin_amdgcn_mfma_f32_16x16x32_bf16(Acur.v, b1, acc1, 0, 0, 0);
            if (s < NSTEP - 1) { Acur = Anext; vcur = vnext; }
        }
#pragma unroll
        for (int i = 0; i < 4; ++i) {
            om_lds[wv][lg * 4 + i][lr]      = acc0[i];
            om_lds[wv][lg * 4 + i][16 + lr] = acc1[i];
        }
    }
    __syncthreads();

    // ---------------- Params: corner offsets + mask-folded bf16 weights ----------------
#pragma unroll
    for (int t = 0; t < 3; ++t) {
        const int kh = lg + t * 4;
        if (kh < 9) {
            const int px = lr;
            const int p2 = pbase + px;
            const int h2 = p2 >> 8, w2 = p2 & 255;
            float offy = om_lds[wv][px][2 * kh]     + b_off[2 * kh];
            float offx = om_lds[wv][px][2 * kh + 1] + b_off[2 * kh + 1];
            float mm   = om_lds[wv][px][18 + kh]    + b_off[18 + kh];
            mm = 1.f / (1.f + __expf(-mm));
            const float sy = (float)(h2 - 1 + kh / 3) + offy;
            const float sx = (float)(w2 - 1 + kh % 3) + offx;
            const float fy = floorf(sy), fx = floorf(sx);
            const int y0 = (int)fy, x0 = (int)fx;
            const float dy = sy - fy, dx = sx - fx;
            const float wy0 = (1.f - dy) * mm, wy1 = dy * mm;
            float w00 = wy0 * (1.f - dx), w01 = wy0 * dx;
            float w10 = wy1 * (1.f - dx), w11 = wy1 * dx;
            const bool vy0 = (unsigned)y0 < HH, vy1 = (unsigned)(y0 + 1) < HH;
            const bool vx0 = (unsigned)x0 < WW, vx1 = (unsigned)(x0 + 1) < WW;
            if (!(vy0 & vx0)) w00 = 0.f;
            if (!(vy0 & vx1)) w01 = 0.f;
            if (!(vy1 & vx0)) w10 = 0.f;
            if (!(vy1 & vx1)) w11 = 0.f;
            const int cy0 = min(max(y0, 0), HH - 1), cy1 = min(max(y0 + 1, 0), HH - 1);
            const int cx0 = min(max(x0, 0), WW - 1), cx1 = min(max(x0 + 1, 0), WW - 1);
            po_lds[wv][px][kh] = make_uint4(
                (uint32_t)((cy0 * WW + cx0) * (CHI * 2)),
                (uint32_t)((cy0 * WW + cx1) * (CHI * 2)),
                (uint32_t)((cy1 * WW + cx0) * (CHI * 2)),
                (uint32_t)((cy1 * WW + cx1) * (CHI * 2)));
            pw_lds[wv][px][kh] = make_uint2(pk2(w00, w01), pk2(w10, w11));
        }
    }
    __syncthreads();

    // ---------------- Phase 2: gather-bilerp + MFMA, depth-1 prefetch pipeline ----------------
    f32x4 acc[4];
#pragma unroll
    for (int n = 0; n < 4; ++n) acc[n] = (f32x4){0.f, 0.f, 0.f, 0.f};

    const char* __restrict__ xh0 = xtb + (lg * 8) * 2;         // half0 channel base
    const char* __restrict__ xh1 = xtb + (32 + lg * 8) * 2;    // half1 channel base

    uint4 po = po_lds[wv][lr][0];
    uint2 pw = pw_lds[wv][lr][0];
    bf16x8 c00a = *(const bf16x8*)(xh0 + po.x);
    bf16x8 c01a = *(const bf16x8*)(xh0 + po.y);
    bf16x8 c10a = *(const bf16x8*)(xh0 + po.z);
    bf16x8 c11a = *(const bf16x8*)(xh0 + po.w);
    bf16x8 c00b = *(const bf16x8*)(xh1 + po.x);
    bf16x8 c01b = *(const bf16x8*)(xh1 + po.y);
    bf16x8 c10b = *(const bf16x8*)(xh1 + po.z);
    bf16x8 c11b = *(const bf16x8*)(xh1 + po.w);

#pragma unroll 1
    for (int kh = 0; kh < 9; ++kh) {
        // issue next tap's corner loads first (depth-1 pipeline)
        uint4 po_n; uint2 pw_n;
        bf16x8 n00a, n01a, n10a, n11a, n00b, n01b, n10b, n11b;
        if (kh < 8) {
            po_n = po_lds[wv][lr][kh + 1];
            pw_n = pw_lds[wv][lr][kh + 1];
            n00a = *(const bf16x8*)(xh0 + po_n.x);
            n01a = *(const bf16x8*)(xh0 + po_n.y);
            n10a = *(const bf16x8*)(xh0 + po_n.z);
            n11a = *(const bf16x8*)(xh0 + po_n.w);
            n00b = *(const bf16x8*)(xh1 + po_n.x);
            n01b = *(const bf16x8*)(xh1 + po_n.y);
            n10b = *(const bf16x8*)(xh1 + po_n.z);
            n11b = *(const bf16x8*)(xh1 + po_n.w);
        }
        const float w00 = bflo(pw.x), w01 = bfhi(pw.x);
        const float w10 = bflo(pw.y), w11 = bfhi(pw.y);

        const bf16x8 A0 = bilerp8(c00a, c01a, c10a, c11a, w00, w01, w10, w11);
        const bf16x8 A1 = bilerp8(c00b, c01b, c10b, c11b, w00, w01, w10, w11);

        const int koff0 = (kh * 2) * 32 + lg * 8;
        const int koff1 = koff0 + 32;
#pragma unroll
        for (int n = 0; n < 4; ++n) {
            bf16x8 bfr = *(const bf16x8*)&g_wB[(size_t)(n * 16 + lr) * KTOT + koff0];
            acc[n] = __builtin_amdgcn_mfma_f32_16x16x32_bf16(A0, bfr, acc[n], 0, 0, 0);
        }
#pragma unroll
        for (int n = 0; n < 4; ++n) {
            bf16x8 bfr = *(const bf16x8*)&g_wB[(size_t)(n * 16 + lr) * KTOT + koff1];
            acc[n] = __builtin_amdgcn_mfma_f32_16x16x32_bf16(A1, bfr, acc[n], 0, 0, 0);
        }
        if (kh < 8) {
            po = po_n; pw = pw_n;
            c00a = n00a; c01a = n01a; c10a = n10a; c11a = n11a;
            c00b = n00b; c01b = n01b; c10b = n10b; c11b = n11b;
        }
    }

    // ---------------- Epilogue ----------------
#pragma unroll
    for (int n = 0; n < 4; ++n) {
        const int o = n * 16 + lr;
        const float bo = bias[o];
        float* op = out + ((size_t)b * CHO + o) * HWSZ + pbase + lg * 4;
        f32x4 r;
#pragma unroll
        for (int i = 0; i < 4; ++i) r[i] = acc[n][i] + bo;
        *(f32x4*)op = r;
    }
}

extern "C" void kernel_launch(void* const* d_in, const int* in_sizes, int n_in,
                              void* d_out, int out_size, void* d_ws, size_t ws_size,
                              hipStream_t stream) {
    const float* x      = (const float*)d_in[0];
    const float* w_off  = (const float*)d_in[1];
    const float* b_off  = (const float*)d_in[2];
    const float* weight = (const float*)d_in[3];
    const float* bias   = (const float*)d_in[4];
    float* out = (float*)d_out;

    prep<<<144, 256, 0, stream>>>(weight, w_off);
    transform<<<2048, 256, 0, stream>>>(x);
    dcn_mfma<<<2048, 256, 0, stream>>>(b_off, bias, out);
}

// Round 6
// 125.807 us; speedup vs baseline: 1.5523x; 1.5523x over previous
//
#include <hip/hip_runtime.h>
#include <math.h>

#define CHI 64
#define CHO 64
#define BB 4
#define HH 128
#define WW 256
#define HWSZ (HH * WW)     // 32768 px per channel plane
#define KTOT 576           // K = khat*64 + c
#define NSTEP 18           // 576 / 32

typedef float f32x4 __attribute__((ext_vector_type(4)));
typedef short bf16x8 __attribute__((ext_vector_type(8)));

// Device-global staging (no ws_size dependence).
__device__ __attribute__((aligned(16))) ushort g_xT[BB * HWSZ * CHI];     // NHWC bf16: [b*HWSZ+px][c]
// Per-lane fragment order: every wave B-load is contiguous 1KB.
__device__ __attribute__((aligned(16))) ushort g_wB2[NSTEP * 4 * 64 * 8];   // [s][n][lane][8]
__device__ __attribute__((aligned(16))) ushort g_wOffB2[NSTEP * 2 * 64 * 8];// [s][j][lane][8]

__device__ __forceinline__ ushort f2bf(float f) {
    uint32_t u = __builtin_bit_cast(uint32_t, f);
    u = (u + 0x7fffu + ((u >> 16) & 1u)) >> 16;   // RNE
    return (ushort)u;
}
__device__ __forceinline__ uint32_t pk2(float a, float b) {
    return (uint32_t)f2bf(a) | ((uint32_t)f2bf(b) << 16);
}
__device__ __forceinline__ float bflo(uint32_t u) { return __builtin_bit_cast(float, u << 16); }
__device__ __forceinline__ float bfhi(uint32_t u) { return __builtin_bit_cast(float, u & 0xffff0000u); }
__device__ __forceinline__ uint32_t cvtpk(float lo, float hi) {
    uint32_t r;
    asm("v_cvt_pk_bf16_f32 %0, %1, %2" : "=v"(r) : "v"(lo), "v"(hi));
    return r;
}

__global__ void prep(const float* __restrict__ weight, const float* __restrict__ w_off) {
    int idx = blockIdx.x * 256 + threadIdx.x;
    if (idx < NSTEP * 4 * 64 * 8) {
        int e = idx & 7, t = idx >> 3;
        int l = t & 63; t >>= 6;
        int n = t & 3, s = t >> 2;
        int o = n * 16 + (l & 15);
        int K = s * 32 + (l >> 4) * 8 + e;
        int kh = K >> 6, c = K & 63;
        g_wB2[idx] = f2bf(weight[(o * CHI + c) * 9 + kh]);
    }
    if (idx < NSTEP * 2 * 64 * 8) {
        int e = idx & 7, t = idx >> 3;
        int l = t & 63; t >>= 6;
        int j = t & 1, s = t >> 1;
        int o = j * 16 + (l & 15);
        int K = s * 32 + (l >> 4) * 8 + e;
        int kh = K >> 6, c = K & 63;
        g_wOffB2[idx] = (o < 27) ? f2bf(w_off[(o * CHI + c) * 9 + kh]) : (ushort)0;
    }
}

// NCHW f32 -> NHWC bf16 transpose. Block = 64 px x 64 ch tile.
__global__ __launch_bounds__(256) void transform(const float* __restrict__ x) {
    __shared__ ushort t[64][68];
    const int tid = threadIdx.x;
    const int wv = tid >> 6, lane = tid & 63;
    const int pb = blockIdx.x * 64;
    const int b = pb >> 15;
    const int pin = pb & (HWSZ - 1);
    const float* __restrict__ xb = x + (size_t)b * CHI * HWSZ + pin;
#pragma unroll
    for (int i = 0; i < 16; ++i) {
        const int c = wv * 16 + i;
        t[lane][c] = f2bf(xb[(size_t)c * HWSZ + lane]);
    }
    __syncthreads();
    const int px = tid >> 2, cb = (tid & 3) * 16;
    const uint32_t* __restrict__ row = (const uint32_t*)&t[px][cb];
    uint4 v0, v1;
    v0.x = row[0]; v0.y = row[1]; v0.z = row[2]; v0.w = row[3];
    v1.x = row[4]; v1.y = row[5]; v1.z = row[6]; v1.w = row[7];
    uint4* __restrict__ dst = (uint4*)&g_xT[(size_t)(pb + px) * CHI + cb];
    dst[0] = v0; dst[1] = v1;
}

union U8 { uint32_t u[4]; bf16x8 v; };

__device__ __forceinline__ bf16x8 bilerp8(bf16x8 v00, bf16x8 v01, bf16x8 v10, bf16x8 v11,
                                          float w00, float w01, float w10, float w11) {
    U8 C00, C01, C10, C11, A;
    C00.v = v00; C01.v = v01; C10.v = v10; C11.v = v11;
#pragma unroll
    for (int j = 0; j < 4; ++j) {
        float se = w00 * bflo(C00.u[j]);
        se = fmaf(w01, bflo(C01.u[j]), se);
        se = fmaf(w10, bflo(C10.u[j]), se);
        se = fmaf(w11, bflo(C11.u[j]), se);
        float so = w00 * bfhi(C00.u[j]);
        so = fmaf(w01, bfhi(C01.u[j]), so);
        so = fmaf(w10, bfhi(C10.u[j]), so);
        so = fmaf(w11, bfhi(C11.u[j]), so);
        A.u[j] = cvtpk(se, so);
    }
    return A.v;
}

// 256 threads = 4 waves; wave = 16 consecutive px; block = 64 px.
__global__ __launch_bounds__(256) void dcn_mfma(
    const float* __restrict__ b_off, const float* __restrict__ bias,
    float* __restrict__ out)
{
    __shared__ float om_lds[4][16][33];
    __shared__ uint4 po_lds[4][16][9];     // corner byte offsets {o00,o01,o10,o11}
    __shared__ uint2 pw_lds[4][16][9];     // packed bf16 corner weights {w00|w01, w10|w11}

    const int tid = threadIdx.x;
    const int wv = tid >> 6, l = tid & 63;
    const int lr = l & 15, lg = l >> 4;
    const int blk = blockIdx.x;
    const int b = blk >> 9;
    const int pbase = (blk & 511) * 64 + wv * 16;
    const char* __restrict__ xtb = (const char*)g_xT + (size_t)b * HWSZ * (CHI * 2);

    // ---------------- Phase 1: offset conv (16px x 27ch) via MFMA, depth-1 prefetch ----------------
    {
        const int p = pbase + lr;
        const int h = p >> 8, w = p & 255;
        f32x4 acc0 = {0.f, 0.f, 0.f, 0.f}, acc1 = {0.f, 0.f, 0.f, 0.f};

        U8 Acur; bool vcur;
        {
            const int iy = h - 1, ix = w - 1;   // s=0 -> kh=0
            vcur = ((unsigned)iy < HH) & ((unsigned)ix < WW);
            const int pidx = vcur ? (iy * WW + ix) : 0;
            Acur.v = *(const bf16x8*)(xtb + (size_t)pidx * (CHI * 2) + (lg * 8) * 2);
        }
#pragma unroll 1
        for (int s = 0; s < NSTEP; ++s) {
            U8 Anext; bool vnext = true;
            if (s < NSTEP - 1) {
                const int sn = s + 1, khn = sn >> 1;
                const int iy = h + (khn / 3) - 1, ix = w + (khn % 3) - 1;
                vnext = ((unsigned)iy < HH) & ((unsigned)ix < WW);
                const int pidx = vnext ? (iy * WW + ix) : 0;
                Anext.v = *(const bf16x8*)(xtb + (size_t)pidx * (CHI * 2) + ((sn & 1) * 32 + lg * 8) * 2);
            }
            if (!vcur) { Acur.u[0] = 0; Acur.u[1] = 0; Acur.u[2] = 0; Acur.u[3] = 0; }
            bf16x8 b0 = *(const bf16x8*)&g_wOffB2[((size_t)(s * 2 + 0) * 64 + l) * 8];
            bf16x8 b1 = *(const bf16x8*)&g_wOffB2[((size_t)(s * 2 + 1) * 64 + l) * 8];
            acc0 = __builtin_amdgcn_mfma_f32_16x16x32_bf16(Acur.v, b0, acc0, 0, 0, 0);
            acc1 = __builtin_amdgcn_mfma_f32_16x16x32_bf16(Acur.v, b1, acc1, 0, 0, 0);
            if (s < NSTEP - 1) { Acur = Anext; vcur = vnext; }
        }
#pragma unroll
        for (int i = 0; i < 4; ++i) {
            om_lds[wv][lg * 4 + i][lr]      = acc0[i];
            om_lds[wv][lg * 4 + i][16 + lr] = acc1[i];
        }
    }
    __syncthreads();

    // ---------------- Params: corner offsets + mask-folded bf16 weights ----------------
#pragma unroll
    for (int t = 0; t < 3; ++t) {
        const int kh = lg + t * 4;
        if (kh < 9) {
            const int px = lr;
            const int p2 = pbase + px;
            const int h2 = p2 >> 8, w2 = p2 & 255;
            float offy = om_lds[wv][px][2 * kh]     + b_off[2 * kh];
            float offx = om_lds[wv][px][2 * kh + 1] + b_off[2 * kh + 1];
            float mm   = om_lds[wv][px][18 + kh]    + b_off[18 + kh];
            mm = 1.f / (1.f + __expf(-mm));
            const float sy = (float)(h2 - 1 + kh / 3) + offy;
            const float sx = (float)(w2 - 1 + kh % 3) + offx;
            const float fy = floorf(sy), fx = floorf(sx);
            const int y0 = (int)fy, x0 = (int)fx;
            const float dy = sy - fy, dx = sx - fx;
            const float wy0 = (1.f - dy) * mm, wy1 = dy * mm;
            float w00 = wy0 * (1.f - dx), w01 = wy0 * dx;
            float w10 = wy1 * (1.f - dx), w11 = wy1 * dx;
            const bool vy0 = (unsigned)y0 < HH, vy1 = (unsigned)(y0 + 1) < HH;
            const bool vx0 = (unsigned)x0 < WW, vx1 = (unsigned)(x0 + 1) < WW;
            if (!(vy0 & vx0)) w00 = 0.f;
            if (!(vy0 & vx1)) w01 = 0.f;
            if (!(vy1 & vx0)) w10 = 0.f;
            if (!(vy1 & vx1)) w11 = 0.f;
            const int cy0 = min(max(y0, 0), HH - 1), cy1 = min(max(y0 + 1, 0), HH - 1);
            const int cx0 = min(max(x0, 0), WW - 1), cx1 = min(max(x0 + 1, 0), WW - 1);
            po_lds[wv][px][kh] = make_uint4(
                (uint32_t)((cy0 * WW + cx0) * (CHI * 2)),
                (uint32_t)((cy0 * WW + cx1) * (CHI * 2)),
                (uint32_t)((cy1 * WW + cx0) * (CHI * 2)),
                (uint32_t)((cy1 * WW + cx1) * (CHI * 2)));
            pw_lds[wv][px][kh] = make_uint2(pk2(w00, w01), pk2(w10, w11));
        }
    }
    __syncthreads();

    // ---------------- Phase 2: gather-bilerp + MFMA, depth-1 prefetch pipeline ----------------
    f32x4 acc[4];
#pragma unroll
    for (int n = 0; n < 4; ++n) acc[n] = (f32x4){0.f, 0.f, 0.f, 0.f};

    const char* __restrict__ xh0 = xtb + (lg * 8) * 2;         // half0 channel base
    const char* __restrict__ xh1 = xtb + (32 + lg * 8) * 2;    // half1 channel base

    uint4 po = po_lds[wv][lr][0];
    uint2 pw = pw_lds[wv][lr][0];
    bf16x8 c00a = *(const bf16x8*)(xh0 + po.x);
    bf16x8 c01a = *(const bf16x8*)(xh0 + po.y);
    bf16x8 c10a = *(const bf16x8*)(xh0 + po.z);
    bf16x8 c11a = *(const bf16x8*)(xh0 + po.w);
    bf16x8 c00b = *(const bf16x8*)(xh1 + po.x);
    bf16x8 c01b = *(const bf16x8*)(xh1 + po.y);
    bf16x8 c10b = *(const bf16x8*)(xh1 + po.z);
    bf16x8 c11b = *(const bf16x8*)(xh1 + po.w);

#pragma unroll 1
    for (int kh = 0; kh < 9; ++kh) {
        // current tap's coalesced B-fragments first (bilerp VALU covers their latency)
        bf16x8 wf0[4], wf1[4];
#pragma unroll
        for (int n = 0; n < 4; ++n) {
            wf0[n] = *(const bf16x8*)&g_wB2[((size_t)((kh * 2 + 0) * 4 + n) * 64 + l) * 8];
            wf1[n] = *(const bf16x8*)&g_wB2[((size_t)((kh * 2 + 1) * 4 + n) * 64 + l) * 8];
        }
        // issue next tap's corner gathers (depth-1 pipeline)
        uint4 po_n; uint2 pw_n;
        bf16x8 n00a, n01a, n10a, n11a, n00b, n01b, n10b, n11b;
        if (kh < 8) {
            po_n = po_lds[wv][lr][kh + 1];
            pw_n = pw_lds[wv][lr][kh + 1];
            n00a = *(const bf16x8*)(xh0 + po_n.x);
            n01a = *(const bf16x8*)(xh0 + po_n.y);
            n10a = *(const bf16x8*)(xh0 + po_n.z);
            n11a = *(const bf16x8*)(xh0 + po_n.w);
            n00b = *(const bf16x8*)(xh1 + po_n.x);
            n01b = *(const bf16x8*)(xh1 + po_n.y);
            n10b = *(const bf16x8*)(xh1 + po_n.z);
            n11b = *(const bf16x8*)(xh1 + po_n.w);
        }
        const float w00 = bflo(pw.x), w01 = bfhi(pw.x);
        const float w10 = bflo(pw.y), w11 = bfhi(pw.y);

        const bf16x8 A0 = bilerp8(c00a, c01a, c10a, c11a, w00, w01, w10, w11);
        const bf16x8 A1 = bilerp8(c00b, c01b, c10b, c11b, w00, w01, w10, w11);

#pragma unroll
        for (int n = 0; n < 4; ++n)
            acc[n] = __builtin_amdgcn_mfma_f32_16x16x32_bf16(A0, wf0[n], acc[n], 0, 0, 0);
#pragma unroll
        for (int n = 0; n < 4; ++n)
            acc[n] = __builtin_amdgcn_mfma_f32_16x16x32_bf16(A1, wf1[n], acc[n], 0, 0, 0);

        if (kh < 8) {
            po = po_n; pw = pw_n;
            c00a = n00a; c01a = n01a; c10a = n10a; c11a = n11a;
            c00b = n00b; c01b = n01b; c10b = n10b; c11b = n11b;
        }
    }

    // ---------------- Epilogue ----------------
#pragma unroll
    for (int n = 0; n < 4; ++n) {
        const int o = n * 16 + lr;
        const float bo = bias[o];
        float* op = out + ((size_t)b * CHO + o) * HWSZ + pbase + lg * 4;
        f32x4 r;
#pragma unroll
        for (int i = 0; i < 4; ++i) r[i] = acc[n][i] + bo;
        *(f32x4*)op = r;
    }
}

extern "C" void kernel_launch(void* const* d_in, const int* in_sizes, int n_in,
                              void* d_out, int out_size, void* d_ws, size_t ws_size,
                              hipStream_t stream) {
    const float* x      = (const float*)d_in[0];
    const float* w_off  = (const float*)d_in[1];
    const float* b_off  = (const float*)d_in[2];
    const float* weight = (const float*)d_in[3];
    const float* bias   = (const float*)d_in[4];
    float* out = (float*)d_out;

    prep<<<144, 256, 0, stream>>>(weight, w_off);
    transform<<<2048, 256, 0, stream>>>(x);
    dcn_mfma<<<2048, 256, 0, stream>>>(b_off, bias, out);
}